// Round 8
// baseline (99.255 us; speedup 1.0000x reference)
//
#include <hip/hip_runtime.h>

// ResidualVQ forward: out[n] = codebook[argmin_k(-2 x.c_k + ||c_k||^2)]
// v8: v7 datapath (swapped-operand MFMA, cn folded via acc-init, bf16-hi
// codebook + split-bf16 x, margin list + exact recheck) with split-K=2:
// each block = 64 rows x 512 codes, grid=1024 -> 4 blocks/CU (100% occ cap).
// Cross-block merge via packed global atomicMin; separate gather kernel.

typedef short bfrag __attribute__((ext_vector_type(8)));  // 8 bf16 = 4 VGPR
typedef float f32x4 __attribute__((ext_vector_type(4)));

constexpr int D = 128;        // embedding dim
constexpr int BR = 64;        // rows per block
constexpr int NTH = 512;      // 8 waves: 4 row-groups (16 rows) x 2 code-halves
constexpr int TC = 64;        // codes per LDS tile
constexpr int KHALF = 512;    // codes per block (split-K = 2)
constexpr int NTILE = 8;      // KHALF / TC
constexpr int LCAP = 1024;    // candidate capacity per block
#define MARGIN 3.25f          // > 2 * max |dist err| (Cauchy-Schwarz, x.cb_lo)

__device__ __forceinline__ unsigned fenc(float f) {  // order-preserving f32->u32
    unsigned u = __float_as_uint(f);
    return (u & 0x80000000u) ? ~u : (u | 0x80000000u);
}
__device__ __forceinline__ float fdec(unsigned e) {
    unsigned u = (e & 0x80000000u) ? (e & 0x7FFFFFFFu) : ~e;
    return __uint_as_float(u);
}
__device__ __forceinline__ unsigned cvtpk(float a, float b) {
    unsigned r;
    asm("v_cvt_pk_bf16_f32 %0, %1, %2" : "=v"(r) : "v"(a), "v"(b));
    return r;
}
union FU { bfrag v; unsigned u[4]; };

// 8 fp32 -> bf16 hi fragment + bf16 lo (residual) fragment
__device__ __forceinline__ void conv8(const float* f, bfrag& hi, bfrag& lo) {
    FU h, l;
#pragma unroll
    for (int m = 0; m < 4; ++m) {
        float a = f[2 * m], b = f[2 * m + 1];
        unsigned hp = cvtpk(a, b);
        float ra = a - __uint_as_float(hp << 16);
        float rb = b - __uint_as_float(hp & 0xFFFF0000u);
        h.u[m] = hp;
        l.u[m] = cvtpk(ra, rb);
    }
    hi = h.v;
    lo = l.v;
}

// --- prep kernel: win init (N threads) + bf16 fragment cast (K*16 threads)
// + exact cnorm (K threads). Grid covers N threads.
__global__ __launch_bounds__(256) void prep_kernel(const float* __restrict__ cb,
                                                   float* __restrict__ cnorm,
                                                   short* __restrict__ hi,
                                                   unsigned long long* __restrict__ win,
                                                   int N, int K) {
    const int tg = blockIdx.x * 256 + threadIdx.x;
    if (tg < N) win[tg] = ~0ull;
    const int NFRAG = K * (D / 8);  // 16384
    if (tg < NFRAG) {
        // fragment t (= cg*256 + ks*64 + lane, lane=kg*16+la) holds
        // cb[cg*16+la][ks*32+kg*8 .. +7], bf16 RN. Coalesced 16B write.
        const int cg = tg >> 8;
        const int r = tg & 255;
        const int ks = r >> 6;
        const int lane = r & 63;
        const int kg = lane >> 4, la = lane & 15;
        const float* src = cb + (size_t)(cg * 16 + la) * D + ks * 32 + kg * 8;
        float4 f0 = *(const float4*)src;
        float4 f1 = *(const float4*)(src + 4);
        FU h;
        h.u[0] = cvtpk(f0.x, f0.y);
        h.u[1] = cvtpk(f0.z, f0.w);
        h.u[2] = cvtpk(f1.x, f1.y);
        h.u[3] = cvtpk(f1.z, f1.w);
        ((bfrag*)hi)[tg] = h.v;
    }
    if (tg < K) {
        const float4* c = (const float4*)(cb + (size_t)tg * D);
        float s0 = 0.f, s1 = 0.f, s2 = 0.f, s3 = 0.f;
#pragma unroll
        for (int i = 0; i < D / 4; ++i) {
            float4 v = c[i];
            s0 = fmaf(v.x, v.x, s0);
            s1 = fmaf(v.y, v.y, s1);
            s2 = fmaf(v.z, v.z, s2);
            s3 = fmaf(v.w, v.w, s3);
        }
        cnorm[tg] = (s0 + s1) + (s2 + s3);
    }
}

__global__ __launch_bounds__(NTH, 8) void vq_mfma(const float* __restrict__ x,
                                                  const float* __restrict__ cb,
                                                  const short* __restrict__ cbh,
                                                  const float* __restrict__ cnorm,
                                                  unsigned long long* __restrict__ win,
                                                  int N, int K) {
    __shared__ short hib[2][TC * D];     // 2 x 16 KB, fragment-linear
    __shared__ float cns[KHALF];         // 2 KB (this block's code half)
    __shared__ unsigned clist[LCAP];     // 4 KB
    __shared__ unsigned rmin[BR];        // 256 B
    __shared__ int ccnt;
    // total ~39 KB -> 4 blocks/CU = 32 waves/CU

    const int bid = blockIdx.x;
    const int kh = bid & 1;              // code half of K (adjacent pairs share rows)
    const int row0 = (bid >> 1) * BR;
    const int kbase0 = kh * KHALF;

    const int tid = threadIdx.x;
    const int lane = tid & 63;
    const int wv = tid >> 6;   // 0..7
    const int rg = wv >> 1;    // row-group (16 rows each)
    const int ch = wv & 1;     // code half of tile (32 codes)
    const int la = lane & 15;
    const int kg = lane >> 4;

    if (tid < BR) rmin[tid] = 0xFF7FFFFFu;
    if (tid == 0) ccnt = 0;
    for (int i = tid; i < KHALF; i += NTH) cns[i] = cnorm[kbase0 + i];

    // ---- (-2x) -> split-bf16 B-fragments in registers (col=la=row, k=kg*8+j) ----
    bfrag xh[4], xl[4];
    {
        const int xrow = row0 + rg * 16 + la;
        const float* xp = x + (size_t)xrow * D + kg * 8;
#pragma unroll
        for (int ks = 0; ks < 4; ++ks) {
            float4 f0 = *(const float4*)(xp + ks * 32);
            float4 f1 = *(const float4*)(xp + ks * 32 + 4);
            float v[8] = {-2.f * f0.x, -2.f * f0.y, -2.f * f0.z, -2.f * f0.w,
                          -2.f * f1.x, -2.f * f1.y, -2.f * f1.z, -2.f * f1.w};
            conv8(v, xh[ks], xl[ks]);
        }
    }

    // ---- pure linear tile staging: ws (fragment order) -> LDS, no VALU ----
    auto stage = [&](int t, int buf) {
        const char* gh = (const char*)cbh + (size_t)(kh * NTILE + t) * 16384
                         + wv * 2048 + lane * 16;
        char* lh = (char*)&hib[buf][0] + wv * 2048;  // wave-uniform base (+lane*16 HW)
        __builtin_amdgcn_global_load_lds(
            (const __attribute__((address_space(1))) uint32_t*)(gh),
            (__attribute__((address_space(3))) uint32_t*)(lh), 16, 0, 0);
        __builtin_amdgcn_global_load_lds(
            (const __attribute__((address_space(1))) uint32_t*)(gh + 1024),
            (__attribute__((address_space(3))) uint32_t*)(lh + 1024), 16, 0, 0);
    };

    stage(0, 0);
    __syncthreads();

    for (int t = 0; t < NTILE; ++t) {
        const int buf = t & 1;
        if (t + 1 < NTILE) stage(t + 1, buf ^ 1);  // loads fly under the MFMAs

        // ---- acc init: hi-chain from cns fragment, lo-chain from 0 ----
        // local code(cf,i) = t*64 + ch*32 + cf*16 + kg*4 + i
        const int cbl = t * TC + ch * 32;
        f32x4 acch[2], accl[2];
        acch[0] = *(const f32x4*)&cns[cbl + kg * 4];
        acch[1] = *(const f32x4*)&cns[cbl + 16 + kg * 4];
        accl[0] = f32x4{0.f, 0.f, 0.f, 0.f};
        accl[1] = f32x4{0.f, 0.f, 0.f, 0.f};

        // ---- compute: 4 ks x 2 cf x 2 chains = 16 MFMA (4 independent chains) ----
        const short* ph = &hib[buf][0];
#pragma unroll
        for (int ks = 0; ks < 4; ++ks) {
            bfrag bh[2];
#pragma unroll
            for (int cf = 0; cf < 2; ++cf) {
                const int off = (ch * 2 + cf) * 2048 + ks * 512 + lane * 8;  // shorts
                bh[cf] = *(const bfrag*)(ph + off);  // lane-linear ds_read_b128
            }
#pragma unroll
            for (int cf = 0; cf < 2; ++cf) {
                // swapped operands: A=codebook, B=x -> C[row=code][col=x-row]
                acch[cf] = __builtin_amdgcn_mfma_f32_16x16x32_bf16(
                    bh[cf], xh[ks], acch[cf], 0, 0, 0);
                accl[cf] = __builtin_amdgcn_mfma_f32_16x16x32_bf16(
                    bh[cf], xl[ks], accl[cf], 0, 0, 0);
            }
        }
        const f32x4 d0 = acch[0] + accl[0];
        const f32x4 d1 = acch[1] + accl[1];
        // d*[i] = cn - 2 x.c  for local code cbl+cf*16+kg*4+i, x-row rg*16+la

        // ---- lane-local epilogue: row-min, margin append, rmin update ----
        {
            float rowmin = fminf(fminf(fminf(d0[0], d0[1]), fminf(d0[2], d0[3])),
                                 fminf(fminf(d1[0], d1[1]), fminf(d1[2], d1[3])));
            rowmin = fminf(rowmin, __shfl_xor(rowmin, 16));
            rowmin = fminf(rowmin, __shfl_xor(rowmin, 32));  // min over tile's 32 codes
            const int row = rg * 16 + la;
            // stale-high rmin is safe (superset append); rowmin covers this tile
            const float thr = fminf(fdec(rmin[row]), rowmin) + MARGIN;
#pragma unroll
            for (int i = 0; i < 4; ++i) {
                if (d0[i] < thr) {
                    int p = atomicAdd(&ccnt, 1);
                    if (p < LCAP)
                        clist[p] = (unsigned)((row << 10) | (kbase0 + cbl + kg * 4 + i));
                }
                if (d1[i] < thr) {
                    int p = atomicAdd(&ccnt, 1);
                    if (p < LCAP)
                        clist[p] = (unsigned)((row << 10) | (kbase0 + cbl + 16 + kg * 4 + i));
                }
            }
            if (kg == 0) atomicMin(&rmin[row], fenc(rowmin));
        }

        __syncthreads();  // drains vmcnt: tile t+1 landed; LDS reads done
    }

    // ---- exact fp32 recheck; packed global atomicMin merges across blocks ----
    const int nc = (ccnt > LCAP) ? LCAP : ccnt;
    for (int b = wv * 4 + kg; b < nc; b += 32) {  // one candidate per 16-lane group
        const unsigned e = clist[b];
        const int row = e >> 10, code = e & 1023;
        const float4* xr4 = (const float4*)(x + (size_t)(row0 + row) * D + la * 8);
        const float4* cr4 = (const float4*)(cb + (size_t)code * D + la * 8);
        float4 a0 = xr4[0], a1 = xr4[1], b0 = cr4[0], b1 = cr4[1];
        float s = a0.x * b0.x;
        s = fmaf(a0.y, b0.y, s); s = fmaf(a0.z, b0.z, s); s = fmaf(a0.w, b0.w, s);
        s = fmaf(a1.x, b1.x, s); s = fmaf(a1.y, b1.y, s);
        s = fmaf(a1.z, b1.z, s); s = fmaf(a1.w, b1.w, s);
#pragma unroll
        for (int off = 1; off <= 8; off <<= 1) s += __shfl_xor(s, off);
        const float dist = fmaf(-2.f, s, cns[code - kbase0]);
        if (la == 0)
            atomicMin(&win[row0 + row],
                      ((unsigned long long)fenc(dist) << 32) | (unsigned)code);
    }
}

// --- gather kernel: out[row] = cb[win[row].code] (coalesced float4) ---
__global__ __launch_bounds__(256) void gather_kernel(const float* __restrict__ cb,
                                                     const unsigned long long* __restrict__ win,
                                                     float* __restrict__ out, int N) {
    const int tg = blockIdx.x * 256 + threadIdx.x;
    const int row = tg >> 2, q = tg & 3;
    if (row >= N) return;
    const int idx = (int)(win[row] & 0xFFFFFFFFull);
    const float4* cs = (const float4*)(cb + (size_t)idx * D + q * 32);
    float4* od = (float4*)(out + (size_t)row * D + q * 32);
#pragma unroll
    for (int i = 0; i < 8; ++i) od[i] = cs[i];
}

extern "C" void kernel_launch(void* const* d_in, const int* in_sizes, int n_in,
                              void* d_out, int out_size, void* d_ws, size_t ws_size,
                              hipStream_t stream) {
    const float* x = (const float*)d_in[0];
    const float* cb = (const float*)d_in[1];
    float* out = (float*)d_out;
    const int N = in_sizes[0] / D;   // 32768
    const int K = in_sizes[1] / D;   // 1024

    float* cnorm = (float*)d_ws;                                   // 4 KB
    short* cbh = (short*)((char*)d_ws + 4096);                     // 256 KB
    unsigned long long* win =
        (unsigned long long*)((char*)d_ws + 4096 + 262144);        // 256 KB

    hipLaunchKernelGGL(prep_kernel, dim3((N + 255) / 256), dim3(256), 0, stream,
                       cb, cnorm, cbh, win, N, K);
    hipLaunchKernelGGL(vq_mfma, dim3(2 * (N / BR)), dim3(NTH), 0, stream,
                       x, cb, cbh, cnorm, win, N, K);
    hipLaunchKernelGGL(gather_kernel, dim3((4 * N + 255) / 256), dim3(256), 0, stream,
                       cb, win, out, N);
}

// Round 9
// 63.817 us; speedup vs baseline: 1.5553x; 1.5553x over previous
//
#include <hip/hip_runtime.h>

// ResidualVQ forward: out[n] = codebook[argmin_k(-2 x.c_k + ||c_k||^2)]
// v9: v8's split-K=2 structure (grid=1024 -> 4 blocks/CU, packed global
// atomicMin merge, separate gather) with v7's register-lean datapath
// (single MFMA chain per cf; fits the 64-VGPR budget of launch_bounds(512,8)
// -> no scratch spill, which was v8's 190MB/dispatch regression).

typedef short bfrag __attribute__((ext_vector_type(8)));  // 8 bf16 = 4 VGPR
typedef float f32x4 __attribute__((ext_vector_type(4)));

constexpr int D = 128;        // embedding dim
constexpr int BR = 64;        // rows per block
constexpr int NTH = 512;      // 8 waves: 4 row-groups (16 rows) x 2 code-halves
constexpr int TC = 64;        // codes per LDS tile
constexpr int KHALF = 512;    // codes per block (split-K = 2)
constexpr int NTILE = 8;      // KHALF / TC
constexpr int LCAP = 1024;    // candidate capacity per block
#define MARGIN 3.25f          // > 2 * max |dist err| (Cauchy-Schwarz, x.cb_lo)

__device__ __forceinline__ unsigned fenc(float f) {  // order-preserving f32->u32
    unsigned u = __float_as_uint(f);
    return (u & 0x80000000u) ? ~u : (u | 0x80000000u);
}
__device__ __forceinline__ float fdec(unsigned e) {
    unsigned u = (e & 0x80000000u) ? (e & 0x7FFFFFFFu) : ~e;
    return __uint_as_float(u);
}
__device__ __forceinline__ unsigned cvtpk(float a, float b) {
    unsigned r;
    asm("v_cvt_pk_bf16_f32 %0, %1, %2" : "=v"(r) : "v"(a), "v"(b));
    return r;
}
union FU { bfrag v; unsigned u[4]; };

// 8 fp32 -> bf16 hi fragment + bf16 lo (residual) fragment
__device__ __forceinline__ void conv8(const float* f, bfrag& hi, bfrag& lo) {
    FU h, l;
#pragma unroll
    for (int m = 0; m < 4; ++m) {
        float a = f[2 * m], b = f[2 * m + 1];
        unsigned hp = cvtpk(a, b);
        float ra = a - __uint_as_float(hp << 16);
        float rb = b - __uint_as_float(hp & 0xFFFF0000u);
        h.u[m] = hp;
        l.u[m] = cvtpk(ra, rb);
    }
    hi = h.v;
    lo = l.v;
}

// --- prep kernel: win init (N threads) + bf16 fragment cast (K*16 threads)
// + exact cnorm (K threads). Grid covers N threads.
__global__ __launch_bounds__(256) void prep_kernel(const float* __restrict__ cb,
                                                   float* __restrict__ cnorm,
                                                   short* __restrict__ hi,
                                                   unsigned long long* __restrict__ win,
                                                   int N, int K) {
    const int tg = blockIdx.x * 256 + threadIdx.x;
    if (tg < N) win[tg] = ~0ull;
    const int NFRAG = K * (D / 8);  // 16384
    if (tg < NFRAG) {
        // fragment t (= cg*256 + ks*64 + lane, lane=kg*16+la) holds
        // cb[cg*16+la][ks*32+kg*8 .. +7], bf16 RN. Coalesced 16B write.
        const int cg = tg >> 8;
        const int r = tg & 255;
        const int ks = r >> 6;
        const int lane = r & 63;
        const int kg = lane >> 4, la = lane & 15;
        const float* src = cb + (size_t)(cg * 16 + la) * D + ks * 32 + kg * 8;
        float4 f0 = *(const float4*)src;
        float4 f1 = *(const float4*)(src + 4);
        FU h;
        h.u[0] = cvtpk(f0.x, f0.y);
        h.u[1] = cvtpk(f0.z, f0.w);
        h.u[2] = cvtpk(f1.x, f1.y);
        h.u[3] = cvtpk(f1.z, f1.w);
        ((bfrag*)hi)[tg] = h.v;
    }
    if (tg < K) {
        const float4* c = (const float4*)(cb + (size_t)tg * D);
        float s0 = 0.f, s1 = 0.f, s2 = 0.f, s3 = 0.f;
#pragma unroll
        for (int i = 0; i < D / 4; ++i) {
            float4 v = c[i];
            s0 = fmaf(v.x, v.x, s0);
            s1 = fmaf(v.y, v.y, s1);
            s2 = fmaf(v.z, v.z, s2);
            s3 = fmaf(v.w, v.w, s3);
        }
        cnorm[tg] = (s0 + s1) + (s2 + s3);
    }
}

__global__ __launch_bounds__(NTH, 8) void vq_mfma(const float* __restrict__ x,
                                                  const float* __restrict__ cb,
                                                  const short* __restrict__ cbh,
                                                  const float* __restrict__ cnorm,
                                                  unsigned long long* __restrict__ win,
                                                  int N, int K) {
    __shared__ short hib[2][TC * D];     // 2 x 16 KB, fragment-linear
    __shared__ float cns[KHALF];         // 2 KB (this block's code half)
    __shared__ unsigned clist[LCAP];     // 4 KB
    __shared__ unsigned rmin[BR];        // 256 B
    __shared__ int ccnt;
    // total ~38.5 KB -> 4 blocks/CU = 32 waves/CU

    const int bid = blockIdx.x;
    const int kh = bid & 1;              // code half of K (adjacent pairs share rows)
    const int row0 = (bid >> 1) * BR;
    const int kbase0 = kh * KHALF;

    const int tid = threadIdx.x;
    const int lane = tid & 63;
    const int wv = tid >> 6;   // 0..7
    const int rg = wv >> 1;    // row-group (16 rows each)
    const int ch = wv & 1;     // code half of tile (32 codes)
    const int la = lane & 15;
    const int kg = lane >> 4;

    if (tid < BR) rmin[tid] = 0xFF7FFFFFu;
    if (tid == 0) ccnt = 0;
    for (int i = tid; i < KHALF; i += NTH) cns[i] = cnorm[kbase0 + i];

    // ---- (-2x) -> split-bf16 B-fragments in registers (col=la=row, k=kg*8+j) ----
    bfrag xh[4], xl[4];
    {
        const int xrow = row0 + rg * 16 + la;
        const float* xp = x + (size_t)xrow * D + kg * 8;
#pragma unroll
        for (int ks = 0; ks < 4; ++ks) {
            float4 f0 = *(const float4*)(xp + ks * 32);
            float4 f1 = *(const float4*)(xp + ks * 32 + 4);
            float v[8] = {-2.f * f0.x, -2.f * f0.y, -2.f * f0.z, -2.f * f0.w,
                          -2.f * f1.x, -2.f * f1.y, -2.f * f1.z, -2.f * f1.w};
            conv8(v, xh[ks], xl[ks]);
        }
    }

    // ---- pure linear tile staging: ws (fragment order) -> LDS, no VALU ----
    auto stage = [&](int t, int buf) {
        const char* gh = (const char*)cbh + (size_t)(kh * NTILE + t) * 16384
                         + wv * 2048 + lane * 16;
        char* lh = (char*)&hib[buf][0] + wv * 2048;  // wave-uniform base (+lane*16 HW)
        __builtin_amdgcn_global_load_lds(
            (const __attribute__((address_space(1))) uint32_t*)(gh),
            (__attribute__((address_space(3))) uint32_t*)(lh), 16, 0, 0);
        __builtin_amdgcn_global_load_lds(
            (const __attribute__((address_space(1))) uint32_t*)(gh + 1024),
            (__attribute__((address_space(3))) uint32_t*)(lh + 1024), 16, 0, 0);
    };

    stage(0, 0);
    __syncthreads();

    for (int t = 0; t < NTILE; ++t) {
        const int buf = t & 1;
        if (t + 1 < NTILE) stage(t + 1, buf ^ 1);  // loads fly under the MFMAs

        // ---- acc init = cns fragment (codes are fragment-linear) ----
        // local code(cf,i) = t*64 + ch*32 + cf*16 + kg*4 + i
        const int cbl = t * TC + ch * 32;
        f32x4 acc[2];
        acc[0] = *(const f32x4*)&cns[cbl + kg * 4];
        acc[1] = *(const f32x4*)&cns[cbl + 16 + kg * 4];

        // ---- compute: 4 ks x 2 cf x 2 terms = 16 MFMA, 8 ds_read_b128 ----
        const short* ph = &hib[buf][0];
#pragma unroll
        for (int ks = 0; ks < 4; ++ks) {
            bfrag bh[2];
#pragma unroll
            for (int cf = 0; cf < 2; ++cf) {
                const int off = (ch * 2 + cf) * 2048 + ks * 512 + lane * 8;  // shorts
                bh[cf] = *(const bfrag*)(ph + off);  // lane-linear ds_read_b128
            }
#pragma unroll
            for (int cf = 0; cf < 2; ++cf) {
                // swapped operands: A=codebook, B=x -> C[row=code][col=x-row]
                acc[cf] = __builtin_amdgcn_mfma_f32_16x16x32_bf16(
                    bh[cf], xh[ks], acc[cf], 0, 0, 0);
                acc[cf] = __builtin_amdgcn_mfma_f32_16x16x32_bf16(
                    bh[cf], xl[ks], acc[cf], 0, 0, 0);
            }
        }
        // acc[cf][i] = cn - 2 x.c  for local code cbl+cf*16+kg*4+i, x-row rg*16+la

        // ---- lane-local epilogue: row-min, margin append, rmin update ----
        {
            float rowmin = fminf(fminf(fminf(acc[0][0], acc[0][1]), fminf(acc[0][2], acc[0][3])),
                                 fminf(fminf(acc[1][0], acc[1][1]), fminf(acc[1][2], acc[1][3])));
            rowmin = fminf(rowmin, __shfl_xor(rowmin, 16));
            rowmin = fminf(rowmin, __shfl_xor(rowmin, 32));  // min over tile's 32 codes
            const int row = rg * 16 + la;
            // stale-high rmin is safe (superset append); rowmin covers this tile
            const float thr = fminf(fdec(rmin[row]), rowmin) + MARGIN;
#pragma unroll
            for (int cf = 0; cf < 2; ++cf)
#pragma unroll
                for (int i = 0; i < 4; ++i) {
                    if (acc[cf][i] < thr) {
                        int p = atomicAdd(&ccnt, 1);
                        if (p < LCAP)
                            clist[p] = (unsigned)((row << 10)
                                                  | (kbase0 + cbl + cf * 16 + kg * 4 + i));
                    }
                }
            if (kg == 0) atomicMin(&rmin[row], fenc(rowmin));
        }

        __syncthreads();  // drains vmcnt: tile t+1 landed; LDS reads done
    }

    // ---- exact fp32 recheck; packed global atomicMin merges across blocks ----
    const int nc = (ccnt > LCAP) ? LCAP : ccnt;
    for (int b = wv * 4 + kg; b < nc; b += 32) {  // one candidate per 16-lane group
        const unsigned e = clist[b];
        const int row = e >> 10, code = e & 1023;
        const float4* xr4 = (const float4*)(x + (size_t)(row0 + row) * D + la * 8);
        const float4* cr4 = (const float4*)(cb + (size_t)code * D + la * 8);
        float4 a0 = xr4[0], a1 = xr4[1], b0 = cr4[0], b1 = cr4[1];
        float s = a0.x * b0.x;
        s = fmaf(a0.y, b0.y, s); s = fmaf(a0.z, b0.z, s); s = fmaf(a0.w, b0.w, s);
        s = fmaf(a1.x, b1.x, s); s = fmaf(a1.y, b1.y, s);
        s = fmaf(a1.z, b1.z, s); s = fmaf(a1.w, b1.w, s);
#pragma unroll
        for (int off = 1; off <= 8; off <<= 1) s += __shfl_xor(s, off);
        const float dist = fmaf(-2.f, s, cns[code - kbase0]);
        if (la == 0)
            atomicMin(&win[row0 + row],
                      ((unsigned long long)fenc(dist) << 32) | (unsigned)code);
    }
}

// --- gather kernel: out[row] = cb[win[row].code] (coalesced float4) ---
__global__ __launch_bounds__(256) void gather_kernel(const float* __restrict__ cb,
                                                     const unsigned long long* __restrict__ win,
                                                     float* __restrict__ out, int N) {
    const int tg = blockIdx.x * 256 + threadIdx.x;
    const int row = tg >> 2, q = tg & 3;
    if (row >= N) return;
    const int idx = (int)(win[row] & 0xFFFFFFFFull);
    const float4* cs = (const float4*)(cb + (size_t)idx * D + q * 32);
    float4* od = (float4*)(out + (size_t)row * D + q * 32);
#pragma unroll
    for (int i = 0; i < 8; ++i) od[i] = cs[i];
}

extern "C" void kernel_launch(void* const* d_in, const int* in_sizes, int n_in,
                              void* d_out, int out_size, void* d_ws, size_t ws_size,
                              hipStream_t stream) {
    const float* x = (const float*)d_in[0];
    const float* cb = (const float*)d_in[1];
    float* out = (float*)d_out;
    const int N = in_sizes[0] / D;   // 32768
    const int K = in_sizes[1] / D;   // 1024

    float* cnorm = (float*)d_ws;                                   // 4 KB
    short* cbh = (short*)((char*)d_ws + 4096);                     // 256 KB
    unsigned long long* win =
        (unsigned long long*)((char*)d_ws + 4096 + 262144);        // 256 KB

    hipLaunchKernelGGL(prep_kernel, dim3((N + 255) / 256), dim3(256), 0, stream,
                       cb, cnorm, cbh, win, N, K);
    hipLaunchKernelGGL(vq_mfma, dim3(2 * (N / BR)), dim3(NTH), 0, stream,
                       x, cb, cbh, cnorm, win, N, K);
    hipLaunchKernelGGL(gather_kernel, dim3((4 * N + 255) / 256), dim3(256), 0, stream,
                       cb, win, out, N);
}

// Round 10
// 47.464 us; speedup vs baseline: 2.0912x; 1.3445x over previous
//
#include <hip/hip_runtime.h>

// ResidualVQ forward: out[n] = codebook[argmin_k(-2 x.c_k + ||c_k||^2)]
// v10: barrier-free K-loop. Codebook pre-split to bf16 fragments in d_ws
// (256 KB, L2-resident); each wave streams B-fragments straight from L2 via
// per-lane global_load_dwordx4, one 32-code tile prefetched in registers.
// No LDS staging, no per-tile __syncthreads. Margin list + exact recheck +
// inline gather (rows exclusive per block). 2 kernels total.

typedef short bfrag __attribute__((ext_vector_type(8)));  // 8 bf16 = 4 VGPR
typedef float f32x4 __attribute__((ext_vector_type(4)));

constexpr int D = 128;      // embedding dim
constexpr int BR = 64;      // rows per block -> grid 512
constexpr int NTH = 512;    // 8 waves: 4 row-groups (16 rows) x 2 K-halves
constexpr int LCAP = 1024;  // candidate capacity per block
#define MARGIN 3.25f        // > 2 * max |approx dist err| (bf16-hi codebook)

__device__ __forceinline__ unsigned fenc(float f) {  // order-preserving f32->u32
    unsigned u = __float_as_uint(f);
    return (u & 0x80000000u) ? ~u : (u | 0x80000000u);
}
__device__ __forceinline__ float fdec(unsigned e) {
    unsigned u = (e & 0x80000000u) ? (e & 0x7FFFFFFFu) : ~e;
    return __uint_as_float(u);
}
__device__ __forceinline__ unsigned cvtpk(float a, float b) {
    unsigned r;
    asm("v_cvt_pk_bf16_f32 %0, %1, %2" : "=v"(r) : "v"(a), "v"(b));
    return r;
}
union FU { bfrag v; unsigned u[4]; };

// 8 fp32 -> bf16 hi fragment + bf16 lo (residual) fragment
__device__ __forceinline__ void conv8(const float* f, bfrag& hi, bfrag& lo) {
    FU h, l;
#pragma unroll
    for (int m = 0; m < 4; ++m) {
        float a = f[2 * m], b = f[2 * m + 1];
        unsigned hp = cvtpk(a, b);
        float ra = a - __uint_as_float(hp << 16);
        float rb = b - __uint_as_float(hp & 0xFFFF0000u);
        h.u[m] = hp;
        l.u[m] = cvtpk(ra, rb);
    }
    hi = h.v;
    lo = l.v;
}

// --- prep: exact cnorm (K threads) + bf16 fragment cast (K*16 threads) ---
// Fragment t (= cg*256 + ks*64 + lane, lane=kg*16+la) holds
// cb[cg*16+la][ks*32+kg*8 .. +7], bf16 RN. Coalesced 16B writes.
__global__ __launch_bounds__(256) void prep_kernel(const float* __restrict__ cb,
                                                   float* __restrict__ cnorm,
                                                   short* __restrict__ hi, int K) {
    const int tg = blockIdx.x * 256 + threadIdx.x;  // 0..16383
    {
        const int cg = tg >> 8;
        const int r = tg & 255;
        const int ks = r >> 6;
        const int lane = r & 63;
        const int kg = lane >> 4, la = lane & 15;
        const float* src = cb + (size_t)(cg * 16 + la) * D + ks * 32 + kg * 8;
        float4 f0 = *(const float4*)src;
        float4 f1 = *(const float4*)(src + 4);
        FU h;
        h.u[0] = cvtpk(f0.x, f0.y);
        h.u[1] = cvtpk(f0.z, f0.w);
        h.u[2] = cvtpk(f1.x, f1.y);
        h.u[3] = cvtpk(f1.z, f1.w);
        ((bfrag*)hi)[tg] = h.v;
    }
    if (tg < K) {
        const float4* c = (const float4*)(cb + (size_t)tg * D);
        float s0 = 0.f, s1 = 0.f, s2 = 0.f, s3 = 0.f;
#pragma unroll
        for (int i = 0; i < D / 4; ++i) {
            float4 v = c[i];
            s0 = fmaf(v.x, v.x, s0);
            s1 = fmaf(v.y, v.y, s1);
            s2 = fmaf(v.z, v.z, s2);
            s3 = fmaf(v.w, v.w, s3);
        }
        cnorm[tg] = (s0 + s1) + (s2 + s3);
    }
}

__global__ __launch_bounds__(NTH, 4) void vq_mfma(const float* __restrict__ x,
                                                  const float* __restrict__ cb,
                                                  const short* __restrict__ cbh,
                                                  const float* __restrict__ cnorm,
                                                  float* __restrict__ out,
                                                  int N, int K) {
    __shared__ float cns[1024];          // 4 KB
    __shared__ unsigned rmin[BR];        // 256 B (fenc-encoded running row min)
    __shared__ unsigned clist[LCAP];     // 4 KB
    __shared__ unsigned long long win[BR];
    __shared__ int ccnt;
    // ~12.8 KB LDS; occupancy VGPR-capped at 4 waves/SIMD

    const int tid = threadIdx.x;
    const int lane = tid & 63;
    const int wv = tid >> 6;   // 0..7
    const int rg = wv >> 1;    // row-group (16 rows)
    const int khw = wv & 1;    // K half (512 codes) this wave covers
    const int la = lane & 15;
    const int kg = lane >> 4;
    const int row0 = blockIdx.x * BR;

    if (tid < BR) { rmin[tid] = 0xFF7FFFFFu; win[tid] = ~0ull; }
    if (tid == 0) ccnt = 0;
    for (int i = tid; i < K; i += NTH) cns[i] = cnorm[i];

    // ---- (-2x) -> split-bf16 B-fragments in registers (col=la=row, k=kg*8+j) ----
    bfrag xh[4], xl[4];
    {
        const int xrow = row0 + rg * 16 + la;
        const float* xp = x + (size_t)xrow * D + kg * 8;
#pragma unroll
        for (int ks = 0; ks < 4; ++ks) {
            float4 f0 = *(const float4*)(xp + ks * 32);
            float4 f1 = *(const float4*)(xp + ks * 32 + 4);
            float v[8] = {-2.f * f0.x, -2.f * f0.y, -2.f * f0.z, -2.f * f0.w,
                          -2.f * f1.x, -2.f * f1.y, -2.f * f1.z, -2.f * f1.w};
            conv8(v, xh[ks], xl[ks]);
        }
    }
    __syncthreads();  // rmin/win/ccnt/cns visible before any appends

    // per-lane fragment pointer for this wave's K half (L2-resident)
    const bfrag* fpb = (const bfrag*)cbh + (size_t)khw * 8192 + lane;
    const int row = rg * 16 + la;  // block-local row this lane owns

    auto load8 = [&](bfrag* dst, int tf) {  // tf = tile's fragment offset (t*512)
        const bfrag* p = fpb + tf;
#pragma unroll
        for (int cf = 0; cf < 2; ++cf)
#pragma unroll
            for (int ks = 0; ks < 4; ++ks)
                dst[cf * 4 + ks] = p[cf * 256 + ks * 64];  // global_load_dwordx4
    };

    auto compute = [&](const bfrag* f, int t) {  // one 32-code tile
        const int cbase = khw * 512 + t * 32;
        f32x4 acc[2];
        acc[0] = *(const f32x4*)&cns[cbase + kg * 4];        // cn folded in
        acc[1] = *(const f32x4*)&cns[cbase + 16 + kg * 4];
#pragma unroll
        for (int ks = 0; ks < 4; ++ks)
#pragma unroll
            for (int cf = 0; cf < 2; ++cf) {
                // swapped operands: A=codebook, B=x -> C[row=code][col=x-row]
                acc[cf] = __builtin_amdgcn_mfma_f32_16x16x32_bf16(
                    f[cf * 4 + ks], xh[ks], acc[cf], 0, 0, 0);
                acc[cf] = __builtin_amdgcn_mfma_f32_16x16x32_bf16(
                    f[cf * 4 + ks], xl[ks], acc[cf], 0, 0, 0);
            }
        // epilogue: acc[cf][i] = dist(code cbase+cf*16+kg*4+i, x-row `row`)
        float m = fminf(fminf(fminf(acc[0][0], acc[0][1]), fminf(acc[0][2], acc[0][3])),
                        fminf(fminf(acc[1][0], acc[1][1]), fminf(acc[1][2], acc[1][3])));
        m = fminf(m, __shfl_xor(m, 16));
        m = fminf(m, __shfl_xor(m, 32));  // min over this tile's 32 codes for `row`
        // stale-high shared rmin is safe (superset append); m covers this tile
        const float thr = fminf(fdec(rmin[row]), m) + MARGIN;
#pragma unroll
        for (int cf = 0; cf < 2; ++cf)
#pragma unroll
            for (int i = 0; i < 4; ++i) {
                if (acc[cf][i] < thr) {
                    int p = atomicAdd(&ccnt, 1);
                    if (p < LCAP)
                        clist[p] = (unsigned)((row << 10)
                                              | (cbase + cf * 16 + kg * 4 + i));
                }
            }
        if (kg == 0) atomicMin(&rmin[row], fenc(m));
    };

    // ---- barrier-free K-loop: 16 tiles, register double-buffer ----
    bfrag cur[8], nxt[8];
    load8(cur, 0);
#pragma unroll 1
    for (int t = 0; t < 16; t += 2) {
        load8(nxt, (t + 1) * 512);   // in flight under compute(cur)
        compute(cur, t);
        if (t + 2 < 16) load8(cur, (t + 2) * 512);  // in flight under compute(nxt)
        compute(nxt, t + 1);
    }

    __syncthreads();  // all appends visible

    // ---- exact fp32 recheck; packed LDS atomicMin keeps lowest idx on ties ----
    const int nc = (ccnt > LCAP) ? LCAP : ccnt;
    for (int b = wv * 4 + kg; b < nc; b += 32) {  // one candidate per 16-lane group
        const unsigned e = clist[b];
        const int crow = e >> 10, code = e & 1023;
        const float4* xr4 = (const float4*)(x + (size_t)(row0 + crow) * D + la * 8);
        const float4* cr4 = (const float4*)(cb + (size_t)code * D + la * 8);
        float4 a0 = xr4[0], a1 = xr4[1], b0 = cr4[0], b1 = cr4[1];
        float s = a0.x * b0.x;
        s = fmaf(a0.y, b0.y, s); s = fmaf(a0.z, b0.z, s); s = fmaf(a0.w, b0.w, s);
        s = fmaf(a1.x, b1.x, s); s = fmaf(a1.y, b1.y, s);
        s = fmaf(a1.z, b1.z, s); s = fmaf(a1.w, b1.w, s);
#pragma unroll
        for (int off = 1; off <= 8; off <<= 1) s += __shfl_xor(s, off);
        const float dist = fmaf(-2.f, s, cns[code]);
        if (la == 0)
            atomicMin(&win[crow],
                      ((unsigned long long)fenc(dist) << 32) | (unsigned)code);
    }
    __syncthreads();

    // ---- gather: out[row] = cb[winner] (coalesced float4) ----
    {
        const int r = tid >> 3, q = tid & 7;  // 64 rows x 8 chunks of 16 floats
        const int idx = (int)(win[r] & 0xFFFFFFFFull);
        const float4* cs = (const float4*)(cb + (size_t)idx * D + q * 16);
        float4* od = (float4*)(out + (size_t)(row0 + r) * D + q * 16);
#pragma unroll
        for (int i = 0; i < 4; ++i) od[i] = cs[i];
    }
}

extern "C" void kernel_launch(void* const* d_in, const int* in_sizes, int n_in,
                              void* d_out, int out_size, void* d_ws, size_t ws_size,
                              hipStream_t stream) {
    const float* x = (const float*)d_in[0];
    const float* cb = (const float*)d_in[1];
    float* out = (float*)d_out;
    const int N = in_sizes[0] / D;   // 32768
    const int K = in_sizes[1] / D;   // 1024

    float* cnorm = (float*)d_ws;                   // 4 KB
    short* cbh = (short*)((char*)d_ws + 4096);     // 256 KB bf16 fragments

    hipLaunchKernelGGL(prep_kernel, dim3(K * 16 / 256), dim3(256), 0, stream,
                       cb, cnorm, cbh, K);
    hipLaunchKernelGGL(vq_mfma, dim3(N / BR), dim3(NTH), 0, stream,
                       x, cb, cbh, cnorm, out, N, K);
}